// Round 8
// baseline (196.363 us; speedup 1.0000x reference)
//
#include <hip/hip_runtime.h>

// PolylineEncoder: h = relu(X@W1+b1); feat = h@W2+b2; masked max over N=64 points.
// B=32 P=512 N=64 C=9 H=128.  Block = 2 polylines (128 points), grid 8192.
// R8: layer2 rebuilt on v_mfma_f32_32x32x16_bf16 computing D[m][d] = H x W2:
//  - mask folded into GEMM as extra K column (H[m][128]=invalid?1:0, W2[128][d]=-4e9)
//  - pooling = in-register max tree over the 16 C regs + shfl_xor(32)
//  - Hs rows stride 146 u16 (=73 dwords, odd) -> conflict-free 32-lane b128 reads
// Layer1 stays on the verified 16x16x32 path.  LDS 37376 B -> 4 blocks/CU.

using bf16x8 = __attribute__((ext_vector_type(8))) short;
using f32x4  = __attribute__((ext_vector_type(4))) float;
using f32x16 = __attribute__((ext_vector_type(16))) float;

#define MFMA16x16(A,B,C) __builtin_amdgcn_mfma_f32_16x16x32_bf16((A),(B),(C),0,0,0)
#define MFMA32x32(A,B,C) __builtin_amdgcn_mfma_f32_32x32x16_bf16((A),(B),(C),0,0,0)

__device__ __forceinline__ f32x4 vmax4(f32x4 a, f32x4 b) {
  return __builtin_elementwise_max(a, b);
}

__device__ __forceinline__ unsigned short f2bf(float f) {
  union { float f; unsigned int u; } v; v.f = f;
  unsigned int r = v.u + 0x7fffu + ((v.u >> 16) & 1u);  // RNE
  return (unsigned short)(r >> 16);
}

// pack two floats to bf16x2 (round-half-up) via v_perm
__device__ __forceinline__ unsigned int pack_bf2(float a, float b) {
  union { float f; unsigned int u; } ua, ub; ua.f = a; ub.f = b;
  return __builtin_amdgcn_perm(ub.u + 0x8000u, ua.u + 0x8000u, 0x07060302u);
}

// ---------------- prep1: mask sniff + frag-swizzled weights ----------------
// ws: w1sw @0 (8192B) | w2sw @8192 (36864B) | flag @45056
__global__ void prep1(const float* __restrict__ W1, const float* __restrict__ W2,
                      const void* __restrict__ mask,
                      unsigned short* __restrict__ w1sw, unsigned short* __restrict__ w2sw,
                      int* __restrict__ flag) {
  int b = blockIdx.x, t = threadIdx.x;
  if (b == 0) {                      // mask storage sniff over 4096 bytes
    __shared__ int cnt;
    if (t == 0) cnt = 0;
    __syncthreads();
    const unsigned char* mb = (const unsigned char*)mask;
    int local = 0;
    for (int i = t * 16; i < t * 16 + 16; i++) local += (mb[i] != 0) ? 1 : 0;
    atomicAdd(&cnt, local);
    __syncthreads();
    if (t == 0) *flag = (cnt > 2800) ? 1 : 0;   // 1 = byte-wise mask, else int32-wise
  } else if (b <= 2) {
    // w1 A-frags (16x16x32): entry e = (wr*4+th)*64 + lane; h=(e>>6)*16+(lane&15)
    int e = (b - 1) * 256 + t;       // 512 entries x 8 halves = 8KB
    int lane = e & 63, grp = e >> 6;
    int li = lane & 15, q = lane >> 4;
    int h = grp * 16 + li;
    int c0 = q * 8;
    #pragma unroll
    for (int j = 0; j < 8; j++) {
      int c = c0 + j;
      w1sw[e * 8 + j] = f2bf((c < 9) ? W1[c * 128 + h] : 0.f);
    }
  } else {
    // w2 B-frags (32x32x16): entry e = (dt*9+kb)*64 + lane; 8 halves each
    // B[k][d]: d = dt*32 + (lane&31), k = kb*16 + (lane>>5)*8 + j
    // k==128 carries the mask penalty row (-4e9); k>128 zero.
    int e = (b - 3) * 256 + t;       // 2304 entries x 8 halves = 36864B
    if (e < 2304) {
      int lane = e & 63, grp = e >> 6;       // grp = dt*9 + kb, 0..35
      int dt = grp / 9, kb = grp - dt * 9;
      int d = dt * 32 + (lane & 31);
      int k0 = kb * 16 + (lane >> 5) * 8;
      #pragma unroll
      for (int j = 0; j < 8; j++) {
        int k = k0 + j;
        float v = (k < 128) ? W2[k * 128 + d] : ((k == 128) ? -4e9f : 0.f);
        w2sw[e * 8 + j] = f2bf(v);
      }
    }
  }
}

// ---------------- main ----------------
// LDS arena 37376 B:
//   [0, 4608)  Xs  raw f32 X block            (b0 .. bfb)
//   whole      Hs  H rows [m][k], stride 146 u16, k:0..127 feat, 128 mask col,
//              129..143 zero                  (bfb .. b2)
//   [0, 2048)  P   per-wave pooled partials   (b2 .. end)
__global__ __launch_bounds__(256, 4) void poly_main_k(
    const float* __restrict__ X, const void* __restrict__ mask,
    const float* __restrict__ b1g, const float* __restrict__ b2g,
    const unsigned short* __restrict__ w1sw, const unsigned short* __restrict__ w2sw,
    const int* __restrict__ flagp, float* __restrict__ out)
{
  __shared__ __align__(16) unsigned char smem[128 * 146 * 2];
  float*          Xs = (float*)smem;
  unsigned short* Hs = (unsigned short*)smem;
  float*          P  = (float*)smem;

  const int tid  = threadIdx.x;
  const int lane = tid & 63;
  const int w    = tid >> 6;
  const int wr   = w >> 1, wc = w & 1;   // layer-1 wave grid: wr = h half, wc = polyline
  const int li   = lane & 15, q = lane >> 4;

  // ---- stage X: 288 float4 coalesced global -> LDS b128 ----
  {
    const f32x4* xg = (const f32x4*)(X + (long long)blockIdx.x * 1152);
    f32x4* xl = (f32x4*)Xs;
    xl[tid] = xg[tid];
    if (tid < 32) xl[tid + 256] = xg[tid + 256];
  }
  __syncthreads();  // b0: Xs ready

  // ---- layer-1 B-frags from Xs: B[m][k], k=q*8+j, only c<9 nonzero ----
  bf16x8 bx[4];
  #pragma unroll
  for (int tm = 0; tm < 4; tm++) {
    int m = wc * 64 + tm * 16 + li;
    const float* xr = Xs + m * 9;
    union { bf16x8 v; unsigned int u[4]; } uu;
    uu.u[0] = uu.u[1] = uu.u[2] = uu.u[3] = 0u;
    if (q == 0) {
      uu.u[0] = pack_bf2(xr[0], xr[1]); uu.u[1] = pack_bf2(xr[2], xr[3]);
      uu.u[2] = pack_bf2(xr[4], xr[5]); uu.u[3] = pack_bf2(xr[6], xr[7]);
    } else if (q == 1) {
      uu.u[0] = pack_bf2(xr[8], 0.f);
    }
    bx[tm] = uu.v;
  }
  __syncthreads();  // bfb: all Xs reads done -> Hs may overwrite arena

  // ---- layer 1 (verified 16x16x32), th-outer, bias in MFMA C-init ----
  #pragma unroll
  for (int th = 0; th < 4; th++) {
    bf16x8 a1 = *(const bf16x8*)(w1sw + ((wr * 4 + th) * 64 + lane) * 8);
    f32x4 bv = *(const f32x4*)(b1g + wr * 64 + th * 16 + q * 4);
    f32x4 acc[4];
    #pragma unroll
    for (int tm = 0; tm < 4; tm++) acc[tm] = bv;
    #pragma unroll
    for (int tm = 0; tm < 4; tm++) acc[tm] = MFMA16x16(a1, bx[tm], acc[tm]);
    // epilogue: relu, pack, write H[m][h] (4 consecutive h per lane -> b64)
    #pragma unroll
    for (int tm = 0; tm < 4; tm++) {
      int m = wc * 64 + tm * 16 + li;
      f32x4 v = vmax4(acc[tm], f32x4{0.f, 0.f, 0.f, 0.f});
      uint2 hv;
      hv.x = pack_bf2(v[0], v[1]);
      hv.y = pack_bf2(v[2], v[3]);
      *(uint2*)(Hs + m * 146 + wr * 64 + th * 16 + q * 4) = hv;
    }
  }

  // ---- mask indicator column: H[m][128] = invalid ? 1 : 0; 129..143 = 0 ----
  {
    int flag = *flagp;
    int m2 = tid >> 1, half = tid & 1;
    long long gi = (long long)blockIdx.x * 128 + m2;
    unsigned int ind = 0u;
    if (half == 0) {
      bool valid = flag ? (((const unsigned char*)mask)[gi] != 0)
                        : (((const int*)mask)[gi] != 0);
      ind = valid ? 0u : 0x00003F80u;   // bf16(1.0) in low u16 (k=128)
    }
    unsigned int* dst = (unsigned int*)(Hs + m2 * 146 + 128) + half * 4;
    dst[0] = ind; dst[1] = 0u; dst[2] = 0u; dst[3] = 0u;
  }
  __syncthreads();  // b1: Hs ready (feat + mask col)

  // ---- layer 2: 32x32x16, D[m][d] = H(A) x W2(B), K=144 (9 ksteps) ----
  // A: row m = w*32 + (lane&31), k = kb*16 + (lane>>5)*8 + j  (ds_read_b128)
  // C/D (verified): col d = lane&31 (+dt*32), row m = (reg&3)+8*(reg>>2)+4*(lane>>5)
  float pool[4];
  {
    const unsigned short* abase = Hs + (w * 32 + (lane & 31)) * 146 + (lane >> 5) * 8;
    #pragma unroll
    for (int dt = 0; dt < 4; dt++) {
      f32x16 acc = {0.f};
      #pragma unroll
      for (int kb = 0; kb < 9; kb++) {
        bf16x8 af = *(const bf16x8*)(abase + kb * 16);
        bf16x8 bf = *(const bf16x8*)(w2sw + ((dt * 9 + kb) * 64 + lane) * 8);
        acc = MFMA32x32(af, bf, acc);
      }
      // pool over the 16 m-rows held in-lane (mask already applied via k=128)
      float p0 = fmaxf(fmaxf(acc[0],  acc[1]),  fmaxf(acc[2],  acc[3]));
      float p1 = fmaxf(fmaxf(acc[4],  acc[5]),  fmaxf(acc[6],  acc[7]));
      float p2 = fmaxf(fmaxf(acc[8],  acc[9]),  fmaxf(acc[10], acc[11]));
      float p3 = fmaxf(fmaxf(acc[12], acc[13]), fmaxf(acc[14], acc[15]));
      float pm = fmaxf(fmaxf(p0, p1), fmaxf(p2, p3));
      pm = fmaxf(pm, __shfl_xor(pm, 32, 64));   // other 4*(lane>>5) m-half
      pool[dt] = pm + b2g[dt * 32 + (lane & 31)];
    }
  }

  __syncthreads();  // b2: all Hs reads done -> reuse arena as P
  // wave w pooled over its 32 m-rows; waves {0,1}=poly0, {2,3}=poly1
  if (lane < 32) {
    #pragma unroll
    for (int dt = 0; dt < 4; dt++)
      P[w * 128 + dt * 32 + lane] = pool[dt];
  }
  __syncthreads();  // b3: P ready

  // ---- final: combine wave pairs, all-invalid -> 0, coalesced store ----
  {
    int p = tid >> 7, d = tid & 127;
    float v = fmaxf(P[(2 * p) * 128 + d], P[(2 * p + 1) * 128 + d]);
    if (v < -1e8f) v = 0.f;
    out[(long long)blockIdx.x * 256 + tid] = v;
  }
}

extern "C" void kernel_launch(void* const* d_in, const int* in_sizes, int n_in,
                              void* d_out, int out_size, void* d_ws, size_t ws_size,
                              hipStream_t stream) {
  const float* X    = (const float*)d_in[0];
  const void*  mask = d_in[1];
  const float* W1   = (const float*)d_in[2];
  const float* b1   = (const float*)d_in[3];
  const float* W2   = (const float*)d_in[4];
  const float* b2   = (const float*)d_in[5];
  float* out = (float*)d_out;

  unsigned short* w1sw = (unsigned short*)d_ws;
  unsigned short* w2sw = (unsigned short*)((char*)d_ws + 8192);
  int* flag            = (int*)((char*)d_ws + 45056);

  prep1<<<12, 256, 0, stream>>>(W1, W2, mask, w1sw, w2sw, flag);
  poly_main_k<<<8192, 256, 0, stream>>>(X, mask, b1, b2, w1sw, w2sw, flag, out);
}

// Round 9
// 144.565 us; speedup vs baseline: 1.3583x; 1.3583x over previous
//
#include <hip/hip_runtime.h>

// PolylineEncoder: h = relu(X@W1+b1); feat = h@W2+b2; masked max over N=64 points.
// B=32 P=512 N=64 C=9 H=128.  Block = 2 polylines (128 points), grid 8192.
// R9 = R7 base (best: 70us) + two changes:
//  1. explicit a2all[16] weight-frag preload (issued before layer1, in flight
//     across the b1 barrier) -- kills the per-tm L1-thrashing reloads that
//     made layer2 latency-exposed (R8 showed tight load->MFMA chains stall).
//  2. Xs gets its own LDS region (no Xs/Hb union) -> one barrier removed.
// LDS 37376 B -> 4 blocks/CU unchanged.  launch_bounds(256,4) (102-reg budget
// of bounds=5 spills: R5/R6 evidence).

using bf16x8 = __attribute__((ext_vector_type(8))) short;
using f32x4  = __attribute__((ext_vector_type(4))) float;

#define MFMA32(A,B,C) __builtin_amdgcn_mfma_f32_16x16x32_bf16((A),(B),(C),0,0,0)

__device__ __forceinline__ f32x4 vmax4(f32x4 a, f32x4 b) {
  return __builtin_elementwise_max(a, b);
}

__device__ __forceinline__ unsigned short f2bf(float f) {
  union { float f; unsigned int u; } v; v.f = f;
  unsigned int r = v.u + 0x7fffu + ((v.u >> 16) & 1u);  // RNE
  return (unsigned short)(r >> 16);
}

// pack two floats to bf16x2 (round-half-up) via v_perm
__device__ __forceinline__ unsigned int pack_bf2(float a, float b) {
  union { float f; unsigned int u; } ua, ub; ua.f = a; ub.f = b;
  return __builtin_amdgcn_perm(ub.u + 0x8000u, ua.u + 0x8000u, 0x07060302u);
}

// ---------------- prep1: mask sniff + frag-swizzled weights ----------------
// ws: w1sw @0 (8KB) | w2sw @8192 (32KB) | flag @40960
__global__ void prep1(const float* __restrict__ W1, const float* __restrict__ W2,
                      const void* __restrict__ mask,
                      unsigned short* __restrict__ w1sw, unsigned short* __restrict__ w2sw,
                      int* __restrict__ flag) {
  int b = blockIdx.x, t = threadIdx.x;
  if (b == 0) {                      // mask storage sniff over 4096 bytes
    __shared__ int cnt;
    if (t == 0) cnt = 0;
    __syncthreads();
    const unsigned char* mb = (const unsigned char*)mask;
    int local = 0;
    for (int i = t * 16; i < t * 16 + 16; i++) local += (mb[i] != 0) ? 1 : 0;
    atomicAdd(&cnt, local);
    __syncthreads();
    if (t == 0) *flag = (cnt > 2800) ? 1 : 0;   // 1 = byte-wise mask, else int32-wise
  } else if (b <= 2) {
    // w1 A-frags (16x16x32): entry e = (wr*4+th)*64 + lane; h=(e>>6)*16+(lane&15)
    int e = (b - 1) * 256 + t;       // 512 entries x 8 halves = 8KB
    int lane = e & 63, grp = e >> 6;
    int li = lane & 15, q = lane >> 4;
    int h = grp * 16 + li;
    int c0 = q * 8;
    #pragma unroll
    for (int j = 0; j < 8; j++) {
      int c = c0 + j;
      w1sw[e * 8 + j] = f2bf((c < 9) ? W1[c * 128 + h] : 0.f);
    }
  } else {
    // w2 A-frags (16x16x32): entry e = (wr*16+ks*4+td)*64 + lane; 8 halves each
    int e = (b - 3) * 256 + t;       // 2048 entries x 8 halves = 32KB
    if (e < 2048) {
      int lane = e & 63, grp = e >> 6;
      int wr = grp >> 4, sub = grp & 15;
      int ks = sub >> 2, td = sub & 3;
      int li = lane & 15, q = lane >> 4;
      int d = wr * 64 + td * 16 + li;
      int h0 = ks * 32 + q * 8;
      #pragma unroll
      for (int j = 0; j < 8; j++)
        w2sw[e * 8 + j] = f2bf(W2[(h0 + j) * 128 + d]);
    }
  }
}

// ---------------- main ----------------
// LDS: Xs (4608 B, own region) + 32768 B arena:
//   arena: Hb  H^T bf16, XOR-swizzled 16B chunks  (b1 .. b2)
//          P   pooled partials f32                (b2 .. end)
__global__ __launch_bounds__(256, 4) void poly_main_k(
    const float* __restrict__ X, const void* __restrict__ mask,
    const float* __restrict__ b1g, const float* __restrict__ b2g,
    const unsigned short* __restrict__ w1sw, const unsigned short* __restrict__ w2sw,
    const int* __restrict__ flagp, float* __restrict__ out)
{
  __shared__ __align__(16) float Xs[1152];
  __shared__ __align__(16) unsigned char arena[32768];
  unsigned short* Hb = (unsigned short*)arena;
  float*          P  = (float*)arena;

  const int tid  = threadIdx.x;
  const int lane = tid & 63;
  const int w    = tid >> 6;
  const int wr   = w >> 1, wc = w & 1;   // wr = h/d half, wc = polyline in block
  const int li   = lane & 15, q = lane >> 4;

  // ---- mask: direct loads; all 4 per lane sit in one 64B line (byte case) ----
  float mf[4];
  {
    int flag = *flagp;
    long long mb = (long long)blockIdx.x * 128 + wc * 64 + li;
    if (flag) {
      const unsigned char* mp = (const unsigned char*)mask;
      #pragma unroll
      for (int tm = 0; tm < 4; tm++) mf[tm] = mp[mb + tm * 16] ? 0.f : -4e9f;
    } else {
      const int* mp = (const int*)mask;
      #pragma unroll
      for (int tm = 0; tm < 4; tm++) mf[tm] = mp[mb + tm * 16] ? 0.f : -4e9f;
    }
  }

  // ---- stage X: 288 float4 coalesced global -> LDS b128 ----
  {
    const f32x4* xg = (const f32x4*)(X + (long long)blockIdx.x * 1152);
    f32x4* xl = (f32x4*)Xs;
    xl[tid] = xg[tid];
    if (tid < 32) xl[tid + 256] = xg[tid + 256];
  }
  __syncthreads();  // b0: Xs ready

  // ---- layer-1 B-frags from Xs: B[m][k], k=q*8+j, only c<9 nonzero ----
  bf16x8 bx[4];
  #pragma unroll
  for (int tm = 0; tm < 4; tm++) {
    int m = wc * 64 + tm * 16 + li;
    const float* xr = Xs + m * 9;
    union { bf16x8 v; unsigned int u[4]; } uu;
    uu.u[0] = uu.u[1] = uu.u[2] = uu.u[3] = 0u;
    if (q == 0) {
      uu.u[0] = pack_bf2(xr[0], xr[1]); uu.u[1] = pack_bf2(xr[2], xr[3]);
      uu.u[2] = pack_bf2(xr[4], xr[5]); uu.u[3] = pack_bf2(xr[6], xr[7]);
    } else if (q == 1) {
      uu.u[0] = pack_bf2(xr[8], 0.f);
    }
    bx[tm] = uu.v;
  }

  // ---- preload ALL layer-2 weight frags NOW (in flight across layer 1) ----
  bf16x8 a2all[16];   // i = ks*4+td; 64 VGPRs, resident through layer 2
  #pragma unroll
  for (int i = 0; i < 16; i++)
    a2all[i] = *(const bf16x8*)(w2sw + ((wr * 16 + i) * 64 + lane) * 8);

  // ---- layer 1, th-outer: bias folded into MFMA C-init ----
  #pragma unroll
  for (int th = 0; th < 4; th++) {
    bf16x8 a1 = *(const bf16x8*)(w1sw + ((wr * 4 + th) * 64 + lane) * 8);
    f32x4 bv = *(const f32x4*)(b1g + wr * 64 + th * 16 + q * 4);
    f32x4 acc[4];
    #pragma unroll
    for (int tm = 0; tm < 4; tm++) acc[tm] = bv;
    #pragma unroll
    for (int tm = 0; tm < 4; tm++) acc[tm] = MFMA32(a1, bx[tm], acc[tm]);
    // epilogue: relu (packed max), pack, swizzled H^T write
    // write chunk (16B units): (wr*8 + th*2 + (q>>1)) ^ li, inner (q&1)*8B
    #pragma unroll
    for (int tm = 0; tm < 4; tm++) {
      int m = wc * 64 + tm * 16 + li;
      f32x4 v = vmax4(acc[tm], f32x4{0.f, 0.f, 0.f, 0.f});
      uint2 hv;
      hv.x = pack_bf2(v[0], v[1]);
      hv.y = pack_bf2(v[2], v[3]);
      int chunk = (wr * 8 + th * 2 + (q >> 1)) ^ li;
      *(uint2*)(Hb + m * 128 + chunk * 8 + (q & 1) * 4) = hv;
    }
  }
  __syncthreads();  // b1: Hb ready

  // ---- layer 2, tm-outer with incremental pool; weights from a2all regs ----
  f32x4 pooled[4];
  #pragma unroll
  for (int tm = 0; tm < 4; tm++) {
    int m = wc * 64 + tm * 16 + li;
    f32x4 acc[4];
    #pragma unroll
    for (int td = 0; td < 4; td++) acc[td] = f32x4{0.f, 0.f, 0.f, 0.f};
    #pragma unroll
    for (int ks = 0; ks < 4; ks++) {
      int chunk = (ks * 4 + q) ^ li;             // read swizzle, 16B aligned
      bf16x8 bb = *(const bf16x8*)(Hb + m * 128 + chunk * 8);
      #pragma unroll
      for (int td = 0; td < 4; td++)
        acc[td] = MFMA32(a2all[ks * 4 + td], bb, acc[td]);
    }
    if (tm == 0) {
      #pragma unroll
      for (int td = 0; td < 4; td++) pooled[td] = acc[td] + mf[0];
    } else {
      #pragma unroll
      for (int td = 0; td < 4; td++) pooled[td] = vmax4(pooled[td], acc[td] + mf[tm]);
    }
  }
  // bias after max (uniform over m)
  #pragma unroll
  for (int td = 0; td < 4; td++)
    pooled[td] += *(const f32x4*)(b2g + wr * 64 + td * 16 + q * 4);

  __syncthreads();  // b2: all Hb reads done -> reuse arena as P
  // P[wc*16+li][d] f32, row stride 132 (pad breaks 2^k bank stride)
  #pragma unroll
  for (int td = 0; td < 4; td++)
    *(f32x4*)(P + (wc * 16 + li) * 132 + wr * 64 + td * 16 + q * 4) = pooled[td];
  __syncthreads();  // b3: P ready

  // ---- final: reduce 16 li-partials per (poly,d), coalesced full-line store ----
  {
    int p = tid >> 7, d = tid & 127;
    const float* Pp = P + p * (16 * 132) + d;
    float v = Pp[0];
    #pragma unroll
    for (int j = 1; j < 16; j++) v = fmaxf(v, Pp[j * 132]);
    if (v < -1e8f) v = 0.f;
    out[(long long)blockIdx.x * 256 + tid] = v;
  }
}

extern "C" void kernel_launch(void* const* d_in, const int* in_sizes, int n_in,
                              void* d_out, int out_size, void* d_ws, size_t ws_size,
                              hipStream_t stream) {
  const float* X    = (const float*)d_in[0];
  const void*  mask = d_in[1];
  const float* W1   = (const float*)d_in[2];
  const float* b1   = (const float*)d_in[3];
  const float* W2   = (const float*)d_in[4];
  const float* b2   = (const float*)d_in[5];
  float* out = (float*)d_out;

  unsigned short* w1sw = (unsigned short*)d_ws;
  unsigned short* w2sw = (unsigned short*)((char*)d_ws + 8192);
  int* flag            = (int*)((char*)d_ws + 40960);

  prep1<<<11, 256, 0, stream>>>(W1, W2, mask, w1sw, w2sw, flag);
  poly_main_k<<<8192, 256, 0, stream>>>(X, mask, b1, b2, w1sw, w2sw, flag, out);
}